// Round 17
// baseline (299.709 us; speedup 1.0000x reference)
//
#include <hip/hip_runtime.h>
#include <hip/hip_bf16.h>
#include <stdint.h>

typedef float  f32x4 __attribute__((ext_vector_type(4)));
typedef short  s16x8 __attribute__((ext_vector_type(8)));
typedef unsigned short u16x8 __attribute__((ext_vector_type(8)));
typedef unsigned short ushort_t;

__device__ __forceinline__ short f2bf(float f) {
  union { float f; unsigned u; } x; x.f = f;
  unsigned r = x.u + 0x7fffu + ((x.u >> 16) & 1u);
  return (short)(r >> 16);
}
__device__ __forceinline__ float bf2f(unsigned short u) {
  union { unsigned u; float f; } x; x.u = ((unsigned)u) << 16; return x.f;
}
__device__ __forceinline__ float i2f(int v) {
  union { int i; float f; } x; x.i = v; return x.f;
}
__device__ __forceinline__ int f2i(float v) {
  union { float f; int i; } x; x.f = v; return x.i;
}

__device__ __forceinline__ void pack_one(const float* W, int cols, int local, short* dst) {
  int NT = cols / 16;
  int j = local & 7, l = (local >> 3) & 63;
  int nt = (local >> 9) % NT;
  int kt = (local >> 9) / NT;
  int k = kt * 32 + ((l >> 4) * 8) + j;
  int ncol = nt * 16 + (l & 15);
  dst[local] = f2bf(W[(size_t)k * cols + ncol]);
}

// ---------------- front: pack(448) | weight-products(128) | bias(1) | build_xin | deg_count
__global__ __launch_bounds__(256)
void k_front(const float* __restrict__ w0, const float* __restrict__ w1,
             const float* __restrict__ w2, const float* __restrict__ w3,
             const float* __restrict__ w4, const float* __restrict__ w5,
             const float* __restrict__ w6, const float* __restrict__ w7,
             short* __restrict__ pk, short* __restrict__ pkprod,
             const float* __restrict__ b21, const float* __restrict__ b22,
             float* __restrict__ fvec,
             const int* __restrict__ t, const float* __restrict__ tw1,
             const float* __restrict__ tb1, const float* __restrict__ tw2,
             const float* __restrict__ tb2,
             const float* __restrict__ xt, const float* __restrict__ cond,
             ushort_t* __restrict__ X, int n,
             const int* __restrict__ edst, int E, int* __restrict__ deg,
             int nbBuild) {
  int b = blockIdx.x;
  if (b < 448) {                        // pack 8 regions
    int i = b * 256 + threadIdx.x;
    if (i < 98304) {
      int r = i >> 14, local = i & 16383;
      const float* W = r == 0 ? w0 : r == 1 ? w1 : r == 2 ? w2 : r == 3 ? w3 : r == 4 ? w4 : w5;
      pack_one(W, 128, local, pk + r * 16384);
    } else {
      int j = i - 98304;
      int r = j >> 13, local = j & 8191;
      pack_one(r ? w7 : w6, 64, local, pk + 98304 + r * 8192);
    }
    return;
  }
  b -= 448;
  if (b < 128) {                        // products: WW_p = W21 @ (p? Wm2 : Wt2), packed
    int p = b >> 6;
    int local = (b & 63) * 256 + threadIdx.x;     // 0..16383
    int jj = local & 7, l = (local >> 3) & 63;
    int nt = (local >> 9) & 7, kt = (local >> 9) >> 3;
    int k = kt * 32 + ((l >> 4) * 8) + jj;
    int ncol = nt * 16 + (l & 15);
    const float* W21f = w2;             // l1_nm_w2 [128][128]
    const float* Wx = p ? (w3 + 16384) : w3;      // l2_nm_w1 mid : top
    float acc = 0.f;
    #pragma unroll 4
    for (int m = 0; m < 128; ++m)
      acc += W21f[(size_t)k * 128 + m] * Wx[(size_t)m * 128 + ncol];
    pkprod[p * 16384 + local] = f2bf(acc);
    return;
  }
  b -= 128;
  if (b == 0) {                         // bias vectors: bv1, bv2, bX
    int tid = threadIdx.x;
    if (tid < 128) {
      float acc = 0.f;
      #pragma unroll 4
      for (int k = 0; k < 128; ++k) acc += b21[k] * w3[(size_t)k * 128 + tid];
      fvec[tid] = acc;                  // bv1 = b21 @ Wt2
      fvec[256 + tid] = b21[tid] + b22[tid];      // bX
    } else {
      int j = tid - 128;
      float acc = 0.f;
      #pragma unroll 4
      for (int k = 0; k < 128; ++k) acc += b21[k] * w3[16384 + (size_t)k * 128 + j];
      fvec[128 + j] = acc;              // bv2 = b21 @ Wm2
    }
    return;
  }
  b -= 1;
  if (b < nbBuild) {                    // build_xin
    __shared__ float h[32], tembL[32];
    int j = threadIdx.x;
    if (j < 32) h[j] = fmaxf(((float)t[0] / 1000.0f) * tw1[j] + tb1[j], 0.f);
    __syncthreads();
    if (j < 32) {
      float acc = tb2[j];
      for (int k2 = 0; k2 < 32; ++k2) acc += h[k2] * tw2[k2 * 32 + j];
      tembL[j] = acc;
    }
    __syncthreads();
    int i = b * 256 + threadIdx.x;
    if (i >= n * 16) return;
    int node = i >> 4, c8 = i & 15;
    float va[8];
    if (c8 < 8)       { const float* p = &xt[(size_t)node * 64 + c8 * 8];
                        #pragma unroll
                        for (int q = 0; q < 8; ++q) va[q] = p[q]; }
    else if (c8 < 12) { const float* p = &cond[(c8 - 8) * 8];
                        #pragma unroll
                        for (int q = 0; q < 8; ++q) va[q] = p[q]; }
    else              { const float* p = &tembL[(c8 - 12) * 8];
                        #pragma unroll
                        for (int q = 0; q < 8; ++q) va[q] = p[q]; }
    u16x8 o;
    #pragma unroll
    for (int q = 0; q < 8; ++q) o[q] = f2bf(va[q]);
    *(u16x8*)&X[(size_t)node * 128 + c8 * 8] = o;
    return;
  }
  b -= nbBuild;                         // deg_count
  int e = b * 256 + threadIdx.x;
  if (e < E) atomicAdd(&deg[edst[e]], 1);
}

// ---------------- scans (self-loop +1 folded in)
__global__ void k_scan1(const int* __restrict__ deg, int* __restrict__ tmp,
                        int* __restrict__ bsum, int n) {
  __shared__ int sh[256];
  int i = blockIdx.x * 256 + threadIdx.x;
  int v = (i < n) ? deg[i] + 1 : 0;
  sh[threadIdx.x] = v; __syncthreads();
  for (int off = 1; off < 256; off <<= 1) {
    int t = (threadIdx.x >= off) ? sh[threadIdx.x - off] : 0;
    __syncthreads();
    sh[threadIdx.x] += t;
    __syncthreads();
  }
  if (i < n) tmp[i] = sh[threadIdx.x];
  if (threadIdx.x == 255) bsum[blockIdx.x] = sh[255];
}
__global__ void k_scan2(int* __restrict__ bsum, int nb) {
  __shared__ int sh[256];
  int t = threadIdx.x;
  int v = (t < nb) ? bsum[t] : 0;
  sh[t] = v; __syncthreads();
  for (int off = 1; off < 256; off <<= 1) {
    int u = (t >= off) ? sh[t - off] : 0;
    __syncthreads();
    sh[t] += u;
    __syncthreads();
  }
  if (t < nb) bsum[t] = sh[t] - v;
}
__global__ void k_scan3(const int* __restrict__ deg, const int* __restrict__ tmp,
                        const int* __restrict__ bsum, int* __restrict__ row,
                        int* __restrict__ cursor, int n) {
  int i = blockIdx.x * 256 + threadIdx.x;
  if (i < n) {
    int incl = tmp[i] + bsum[i >> 8];
    row[i + 1] = incl;
    cursor[(size_t)i * 32] = incl - (deg[i] + 1);
    if (i == 0) row[0] = 0;
  }
}

// ---------------- hybrid: scatter (blocks < nscat) || quad GEMM (P1,Q1,P2a,Q2a)
__global__ __launch_bounds__(256)
void k_quad_scatter(const ushort_t* __restrict__ A, const short* __restrict__ pk,
                    const float* __restrict__ bias1,
                    ushort_t* __restrict__ P1, ushort_t* __restrict__ Q1,
                    ushort_t* __restrict__ P2a, ushort_t* __restrict__ Q2a,
                    int n, int nscat,
                    const int* __restrict__ ei, int E, int nE,
                    int* __restrict__ cursor, int4* __restrict__ csr32,
                    const float* __restrict__ pos,
                    const float* __restrict__ cw1, const float* __restrict__ cb1,
                    const float* __restrict__ cw2, const float* __restrict__ cb2) {
  __shared__ short BL[128 * 128];       // 32KB
  if ((int)blockIdx.x < nscat) {
    int e = blockIdx.x * 256 + threadIdx.x;
    if (e >= nE) return;
    int s, d, id;
    if (e < E) { s = ei[e]; d = ei[E + e]; id = e; }
    else       { s = d = e - E; id = -1; }
    int slot = atomicAdd(&cursor[(size_t)d * 32], 1);
    float dx = pos[s*3+0] - pos[d*3+0];
    float dy = pos[s*3+1] - pos[d*3+1];
    float dz = pos[s*3+2] - pos[d*3+2];
    float dist = sqrtf(dx*dx + dy*dy + dz*dz + 1e-8f);
    float hh = cb2[0];
    #pragma unroll 4
    for (int j = 0; j < 128; ++j)
      hh += fmaxf(fmaf(dist, cw1[j], cb1[j]), 0.f) * cw2[j];
    int4 c0; c0.x = s; c0.y = d; c0.z = id; c0.w = f2i(dist);
    int4 c1; c1.x = f2i(hh * dx); c1.y = f2i(hh * dy); c1.z = f2i(hh * dz); c1.w = 0;
    csr32[(size_t)slot * 2 + 0] = c0;
    csr32[(size_t)slot * 2 + 1] = c1;
    return;
  }
  // quad GEMM: phases {Wt1, Wm1, Wt2, Wm2} at int4 offsets {0,2048,6144,8192}
  const int NT = 8;
  int gb = blockIdx.x - nscat;
  int t = threadIdx.x, wid = t >> 6, lane = t & 63;
  int cg = lane >> 4;
  int ntiles = (n + 15) >> 4;
  int tile = gb * 4 + wid;
  bool valid = tile < ntiles;
  int r0 = (valid ? tile : 0) << 4;
  int arow = r0 + (lane & 15);
  int crow = arow < n ? arow : 0;
  const ushort_t* Ar = A + (size_t)crow * 128;
  s16x8 Af[4];
  #pragma unroll
  for (int kt = 0; kt < 4; ++kt)
    Af[kt] = *(const s16x8*)(Ar + kt * 32 + cg * 8);
  float bb[NT];
  #pragma unroll
  for (int nt = 0; nt < NT; ++nt)
    bb[nt] = bias1[nt * 16 + (lane & 15)];
  const int offs[4] = {0, 2048, 6144, 8192};
  ushort_t* outs0 = P1;
  #pragma unroll
  for (int ph = 0; ph < 4; ++ph) {
    ushort_t* outp = ph == 0 ? P1 : ph == 1 ? Q1 : ph == 2 ? P2a : Q2a;
    for (int i = threadIdx.x; i < 2048; i += 256)
      ((int4*)BL)[i] = ((const int4*)pk)[offs[ph] + i];
    __syncthreads();
    #pragma unroll
    for (int nt = 0; nt < NT; ++nt) {
      f32x4 acc = {0.f, 0.f, 0.f, 0.f};
      #pragma unroll
      for (int kt = 0; kt < 4; ++kt) {
        s16x8 bfr = *(const s16x8*)&BL[((kt * NT + nt) * 64 + lane) * 8];
        acc = __builtin_amdgcn_mfma_f32_16x16x32_bf16(Af[kt], bfr, acc, 0, 0, 0);
      }
      int ncol = nt * 16 + (lane & 15);
      float badd = ph == 0 ? bb[nt] : 0.f;
      #pragma unroll
      for (int reg = 0; reg < 4; ++reg) {
        int rr = r0 + cg * 4 + reg;
        if (valid && rr < n)
          outp[(size_t)rr * 128 + ncol] = (ushort_t)f2bf(acc[reg] + badd);
      }
    }
    __syncthreads();
  }
  (void)outs0;
}

// ---------------- hybrid: dual-resid GEMM (P2,Q2 from S1) || aux2 (layer-2 dist)
__global__ __launch_bounds__(256)
void k_dualresid_aux(const ushort_t* __restrict__ S1, const short* __restrict__ pkprod,
                     const float* __restrict__ fvec, const float* __restrict__ bc1,
                     const ushort_t* __restrict__ P2a, const ushort_t* __restrict__ Q2a,
                     const float* __restrict__ degf,
                     ushort_t* __restrict__ P2, ushort_t* __restrict__ Q2,
                     int n, int ngemm,
                     const int4* __restrict__ csr32, int nE,
                     const float* __restrict__ pos1, float* __restrict__ auxd) {
  __shared__ short BL[128 * 128];
  if ((int)blockIdx.x < ngemm) {
    const int NT = 8;
    int t = threadIdx.x, wid = t >> 6, lane = t & 63;
    int cg = lane >> 4;
    int ntiles = (n + 15) >> 4;
    int tile = blockIdx.x * 4 + wid;
    bool valid = tile < ntiles;
    int r0 = (valid ? tile : 0) << 4;
    int arow = r0 + (lane & 15);
    int crow = arow < n ? arow : 0;
    const ushort_t* Ar = S1 + (size_t)crow * 128;
    s16x8 Af[4];
    #pragma unroll
    for (int kt = 0; kt < 4; ++kt)
      Af[kt] = *(const s16x8*)(Ar + kt * 32 + cg * 8);
    float dsc[4];
    #pragma unroll
    for (int reg = 0; reg < 4; ++reg) {
      int rr = r0 + cg * 4 + reg;
      dsc[reg] = degf[rr < n ? rr : 0];
    }
    #pragma unroll
    for (int ph = 0; ph < 2; ++ph) {
      for (int i = threadIdx.x; i < 2048; i += 256)
        ((int4*)BL)[i] = ((const int4*)pkprod)[ph * 2048 + i];
      __syncthreads();
      ushort_t* outp = ph ? Q2 : P2;
      const ushort_t* residp = ph ? Q2a : P2a;
      #pragma unroll
      for (int nt = 0; nt < NT; ++nt) {
        f32x4 acc = {0.f, 0.f, 0.f, 0.f};
        #pragma unroll
        for (int kt = 0; kt < 4; ++kt) {
          s16x8 bfr = *(const s16x8*)&BL[((kt * NT + nt) * 64 + lane) * 8];
          acc = __builtin_amdgcn_mfma_f32_16x16x32_bf16(Af[kt], bfr, acc, 0, 0, 0);
        }
        int ncol = nt * 16 + (lane & 15);
        float bv = fvec[ph * 128 + ncol];
        float bc = ph ? 0.f : bc1[ncol];
        #pragma unroll
        for (int reg = 0; reg < 4; ++reg) {
          int rr = r0 + cg * 4 + reg;
          if (valid && rr < n) {
            float v = acc[reg] + dsc[reg] * bv + bc + bf2f(residp[(size_t)rr * 128 + ncol]);
            outp[(size_t)rr * 128 + ncol] = (ushort_t)f2bf(v);
          }
        }
      }
      __syncthreads();
    }
    return;
  }
  int k = (blockIdx.x - ngemm) * 256 + threadIdx.x;
  if (k >= nE) return;
  int4 c = csr32[(size_t)k * 2];
  int s = c.x, d = c.y;
  float dx = pos1[s*3+0] - pos1[d*3+0];
  float dy = pos1[s*3+1] - pos1[d*3+1];
  float dz = pos1[s*3+2] - pos1[d*3+2];
  auxd[k] = sqrtf(dx*dx + dy*dy + dz*dz + 1e-8f);
}

// ---------------- final: X2 = X0 + S1@W21 + S2@W22 + degf*bX -> d_out + U,V (LDS transpose)
__global__ __launch_bounds__(256)
void k_final(const ushort_t* __restrict__ S1, const ushort_t* __restrict__ S2,
             const ushort_t* __restrict__ X0b, const float* __restrict__ degf,
             const float* __restrict__ bX, const short* __restrict__ pk,
             const float* __restrict__ bpb1,
             float* __restrict__ out64, ushort_t* __restrict__ U, ushort_t* __restrict__ V,
             int n) {
  __shared__ short BL[16384];           // 32KB weights
  __shared__ short XL[4 * 16 * 136];    // X2 tiles, padded rows
  const int NT = 8;
  int t = threadIdx.x, wid = t >> 6, lane = t & 63;
  int cg = lane >> 4;
  int ntiles = (n + 15) >> 4;
  int tile = blockIdx.x * 4 + wid;
  bool valid = tile < ntiles;
  int r0 = (valid ? tile : 0) << 4;
  int arow = r0 + (lane & 15);
  int crow = arow < n ? arow : 0;
  float dsc[4];
  #pragma unroll
  for (int reg = 0; reg < 4; ++reg) {
    int rr = r0 + cg * 4 + reg;
    dsc[reg] = degf[rr < n ? rr : 0];
  }
  f32x4 acc[NT];
  #pragma unroll
  for (int nt = 0; nt < NT; ++nt) acc[nt] = (f32x4){0.f, 0.f, 0.f, 0.f};
  // phase A/B: accumulate S1@W21 then S2@W22  (W21 at int4 off 4096, W22 at 10240)
  #pragma unroll
  for (int ph = 0; ph < 2; ++ph) {
    const ushort_t* Sp = ph ? S2 : S1;
    int woff = ph ? 10240 : 4096;
    for (int i = threadIdx.x; i < 2048; i += 256)
      ((int4*)BL)[i] = ((const int4*)pk)[woff + i];
    __syncthreads();
    const ushort_t* Ar = Sp + (size_t)crow * 128;
    s16x8 Af[4];
    #pragma unroll
    for (int kt = 0; kt < 4; ++kt)
      Af[kt] = *(const s16x8*)(Ar + kt * 32 + cg * 8);
    #pragma unroll
    for (int nt = 0; nt < NT; ++nt) {
      #pragma unroll
      for (int kt = 0; kt < 4; ++kt) {
        s16x8 bfr = *(const s16x8*)&BL[((kt * NT + nt) * 64 + lane) * 8];
        acc[nt] = __builtin_amdgcn_mfma_f32_16x16x32_bf16(Af[kt], bfr, acc[nt], 0, 0, 0);
      }
    }
    __syncthreads();
  }
  // epilogue: X2 = acc + degf*bX + X0; write d_out cols<64; stash bf16 X2 in XL
  int xbase = wid * 16 * 136;
  #pragma unroll
  for (int nt = 0; nt < NT; ++nt) {
    int ncol = nt * 16 + (lane & 15);
    float bxv = bX[ncol];
    #pragma unroll
    for (int reg = 0; reg < 4; ++reg) {
      int rr = r0 + cg * 4 + reg;
      float v = acc[nt][reg] + dsc[reg] * bxv;
      if (valid && rr < n) v += bf2f(X0b[(size_t)rr * 128 + ncol]);
      if (valid && rr < n && ncol < 64) out64[(size_t)rr * 64 + ncol] = v;
      XL[xbase + (cg * 4 + reg) * 136 + ncol] = f2bf(v);
    }
  }
  __syncthreads();
  // phase C: stage bp_t|bp_b (int4 off 12288, 2048), U,V from XL A-frags
  for (int i = threadIdx.x; i < 2048; i += 256)
    ((int4*)BL)[i] = ((const int4*)pk)[12288 + i];
  __syncthreads();
  s16x8 Ax[4];
  #pragma unroll
  for (int kt = 0; kt < 4; ++kt)
    Ax[kt] = *(const s16x8*)&XL[xbase + (lane & 15) * 136 + kt * 32 + cg * 8];
  #pragma unroll
  for (int w = 0; w < 2; ++w) {
    ushort_t* outp = w ? V : U;
    const short* BLc = BL + w * 8192;
    #pragma unroll
    for (int nt = 0; nt < 4; ++nt) {
      f32x4 a4 = {0.f, 0.f, 0.f, 0.f};
      #pragma unroll
      for (int kt = 0; kt < 4; ++kt) {
        s16x8 bfr = *(const s16x8*)&BLc[((kt * 4 + nt) * 64 + lane) * 8];
        a4 = __builtin_amdgcn_mfma_f32_16x16x32_bf16(Ax[kt], bfr, a4, 0, 0, 0);
      }
      int ncol = nt * 16 + (lane & 15);
      float badd = w ? 0.f : bpb1[ncol];
      #pragma unroll
      for (int reg = 0; reg < 4; ++reg) {
        int rr = r0 + cg * 4 + reg;
        if (valid && rr < n)
          outp[(size_t)rr * 64 + ncol] = (ushort_t)f2bf(a4[reg] + badd);
      }
    }
  }
}

// ---------------- per-dst aggregation (half-stream pipeline, csr32 reads)
template<bool L1>
__global__ __launch_bounds__(256)
void k_aggregate(const int* __restrict__ row, const int4* __restrict__ csr32,
                 const float* __restrict__ auxd,
                 const ushort_t* __restrict__ Pb, const ushort_t* __restrict__ Qb,
                 const float* __restrict__ w1r,
                 const float* __restrict__ posin, float* __restrict__ posout,
                 float* __restrict__ degf, ushort_t* __restrict__ Sb, int n) {
  int gw = (blockIdx.x * 256 + threadIdx.x) >> 6;
  if (gw >= n) return;
  int lane = threadIdx.x & 63;
  int half = lane >> 5, sub = lane & 31;
  int r0 = row[gw], r1 = row[gw + 1];
  int r1m1 = r1 - 1;

  ushort4 pu = *(const ushort4*)&Pb[(size_t)gw * 128 + (sub << 2)];
  float p0 = bf2f(pu.x), p1 = bf2f(pu.y), p2 = bf2f(pu.z), p3 = bf2f(pu.w);
  float4 wv = *(const float4*)&w1r[sub << 2];
  float a0 = 0.f, a1 = 0.f, a2 = 0.f, a3 = 0.f, pacc = 0.f;

  int k0 = r0 + half;
  bool any = k0 < r1;
  int kA = k0 < r1m1 ? k0 : r1m1;
  int kB = k0 + 2 < r1m1 ? k0 + 2 : r1m1;
  int4 cA = csr32[(size_t)kA * 2];
  int sB = csr32[(size_t)kB * 2].x;
  ushort4 qA = *(const ushort4*)&Qb[(size_t)cA.x * 128 + (sub << 2)];
  float dA, dB;
  float4 hA, hB;
  if (L1) { hA = *(const float4*)&csr32[(size_t)kA * 2 + 1]; dA = i2f(cA.w); }
  else    { dA = auxd[kA]; }

  for (int k = k0; k + 2 < r1; k += 2) {
    int kn4 = k + 4 < r1m1 ? k + 4 : r1m1;
    int kc2 = k + 2;
    int sC = csr32[(size_t)kn4 * 2].x;
    ushort4 qB = *(const ushort4*)&Qb[(size_t)sB * 128 + (sub << 2)];
    if (L1) {
      int4 cB2 = csr32[(size_t)kc2 * 2];
      hB = *(const float4*)&csr32[(size_t)kc2 * 2 + 1];
      dB = i2f(cB2.w);
    } else {
      dB = auxd[kc2];
    }
    a0 += fmaxf(fmaf(dA, wv.x, p0 + bf2f(qA.x)), 0.f);
    a1 += fmaxf(fmaf(dA, wv.y, p1 + bf2f(qA.y)), 0.f);
    a2 += fmaxf(fmaf(dA, wv.z, p2 + bf2f(qA.z)), 0.f);
    a3 += fmaxf(fmaf(dA, wv.w, p3 + bf2f(qA.w)), 0.f);
    if (L1 && sub < 3) pacc += (sub == 0) ? hA.x : (sub == 1) ? hA.y : hA.z;
    qA = qB; dA = dB; hA = hB; sB = sC;
  }
  if (any) {
    a0 += fmaxf(fmaf(dA, wv.x, p0 + bf2f(qA.x)), 0.f);
    a1 += fmaxf(fmaf(dA, wv.y, p1 + bf2f(qA.y)), 0.f);
    a2 += fmaxf(fmaf(dA, wv.z, p2 + bf2f(qA.z)), 0.f);
    a3 += fmaxf(fmaf(dA, wv.w, p3 + bf2f(qA.w)), 0.f);
    if (L1 && sub < 3) pacc += (sub == 0) ? hA.x : (sub == 1) ? hA.y : hA.z;
  }

  a0 += __shfl_xor(a0, 32, 64);
  a1 += __shfl_xor(a1, 32, 64);
  a2 += __shfl_xor(a2, 32, 64);
  a3 += __shfl_xor(a3, 32, 64);
  if (L1) pacc += __shfl_xor(pacc, 32, 64);

  if (half == 0) {
    ushort4 o;
    o.x = (ushort_t)f2bf(a0); o.y = (ushort_t)f2bf(a1);
    o.z = (ushort_t)f2bf(a2); o.w = (ushort_t)f2bf(a3);
    *(ushort4*)&Sb[(size_t)gw * 128 + (sub << 2)] = o;
  }
  if (L1) {
    if (lane < 3) posout[gw * 3 + lane] = posin[gw * 3 + lane] + pacc;
    if (lane == 0) degf[gw] = (float)(r1 - r0);
  }
}

// ---------------- bond predictor in CSR(dst) order
__global__ __launch_bounds__(256)
void k_bond(const int4* __restrict__ csr32, int nE,
            const ushort_t* __restrict__ U, const ushort_t* __restrict__ V,
            const float* __restrict__ w2, const float* __restrict__ b2,
            float* __restrict__ out) {
  __shared__ float w2L[256];
  w2L[threadIdx.x] = w2[threadIdx.x];
  __syncthreads();
  int k = blockIdx.x * 256 + threadIdx.x;
  if (k >= nE) return;
  int4 c = csr32[(size_t)k * 2];
  int eid = c.z;
  if (eid < 0) return;
  int s = c.x, d = c.y;
  const ushort_t* Ur = U + (size_t)s * 64;
  const ushort_t* Vr = V + (size_t)d * 64;
  float l0 = b2[0], l1 = b2[1], l2 = b2[2], l3 = b2[3];
  #pragma unroll
  for (int c8 = 0; c8 < 8; ++c8) {
    u16x8 u = *(const u16x8*)(Ur + c8 * 8);
    u16x8 v = *(const u16x8*)(Vr + c8 * 8);
    #pragma unroll
    for (int j = 0; j < 8; ++j) {
      float h = fmaxf(bf2f(u[j]) + bf2f(v[j]), 0.f);
      const float* wr = &w2L[(c8 * 8 + j) * 4];
      l0 = fmaf(h, wr[0], l0);
      l1 = fmaf(h, wr[1], l1);
      l2 = fmaf(h, wr[2], l2);
      l3 = fmaf(h, wr[3], l3);
    }
  }
  float4 o = {l0, l1, l2, l3};
  *(float4*)&out[(size_t)eid * 4] = o;
}

extern "C" void kernel_launch(void* const* d_in, const int* in_sizes, int n_in,
                              void* d_out, int out_size, void* d_ws, size_t ws_size,
                              hipStream_t stream) {
  const float* x_t   = (const float*)d_in[0];
  const float* pos   = (const float*)d_in[1];
  const int*   ei    = (const int*)d_in[2];
  const int*   tt    = (const int*)d_in[3];
  const float* cond  = (const float*)d_in[4];
  const float* te_w1 = (const float*)d_in[5];
  const float* te_b1 = (const float*)d_in[6];
  const float* te_w2 = (const float*)d_in[7];
  const float* te_b2 = (const float*)d_in[8];
  const float* l1_nm_w1 = (const float*)d_in[9];
  const float* l1_nm_b1 = (const float*)d_in[10];
  const float* l1_nm_w2 = (const float*)d_in[11];
  const float* l1_nm_b2 = (const float*)d_in[12];
  const float* l1_cm_w1 = (const float*)d_in[13];
  const float* l1_cm_b1 = (const float*)d_in[14];
  const float* l1_cm_w2 = (const float*)d_in[15];
  const float* l1_cm_b2 = (const float*)d_in[16];
  const float* l2_nm_w1 = (const float*)d_in[17];
  const float* l2_nm_b1 = (const float*)d_in[18];
  const float* l2_nm_w2 = (const float*)d_in[19];
  const float* l2_nm_b2 = (const float*)d_in[20];
  const float* bp_w1 = (const float*)d_in[25];
  const float* bp_b1 = (const float*)d_in[26];
  const float* bp_w2 = (const float*)d_in[27];
  const float* bp_b2 = (const float*)d_in[28];

  int n  = in_sizes[0] / 64;
  int E_ = in_sizes[2] / 2;
  int nE = E_ + n;
  int nb = (n + 255) / 256;

  uintptr_t base = (uintptr_t)d_ws;
  size_t off = 0;
  auto alloc = [&](size_t bytes) -> void* {
    void* p = (void*)(base + off);
    off += (bytes + 255) & ~(size_t)255;
    return p;
  };
  short* pk     = (short*)alloc(114688 * 2);
  short* pkprod = (short*)alloc(32768 * 2);
  float* fvec   = (float*)alloc(384 * 4);
  ushort_t* X0b = (ushort_t*)alloc((size_t)n * 128 * 2);
  ushort_t* Pbf = (ushort_t*)alloc((size_t)n * 128 * 2);   // P1 then P2
  ushort_t* Qbf = (ushort_t*)alloc((size_t)n * 128 * 2);   // Q1 then Q2
  ushort_t* P2a = (ushort_t*)alloc((size_t)n * 128 * 2);
  ushort_t* Q2a = (ushort_t*)alloc((size_t)n * 128 * 2);
  ushort_t* Sb1 = (ushort_t*)alloc((size_t)n * 128 * 2);
  ushort_t* Sb2 = (ushort_t*)alloc((size_t)n * 128 * 2);
  ushort_t* Ubf = (ushort_t*)alloc((size_t)n * 64 * 2);
  ushort_t* Vbf = (ushort_t*)alloc((size_t)n * 64 * 2);
  int*   deg    = (int*)alloc((size_t)n * 4);
  int*   tmp    = (int*)alloc((size_t)n * 4);
  int*   bsum   = (int*)alloc(256 * 4);
  int*   rowp   = (int*)alloc(((size_t)n + 1) * 4);
  int*   cursor = (int*)alloc((size_t)n * 128);
  int4*  csr32  = (int4*)alloc((size_t)nE * 32);
  float* auxd   = (float*)alloc((size_t)nE * 4);
  float* degf   = (float*)alloc((size_t)n * 4);
  float* pos1   = (float*)alloc((size_t)n * 3 * 4);

  int nbBuild = (n * 16 + 255) / 256;
  int ndc = (E_ + 255) / 256;
  int nscat = (nE + 255) / 256;
  int nagg = (n + 3) / 4;
  int ngemm = (((n + 15) >> 4) + 3) / 4;

  hipMemsetAsync(deg, 0, (size_t)n * 4, stream);
  k_front<<<448 + 128 + 1 + nbBuild + ndc, 256, 0, stream>>>(
      l1_nm_w1, l1_nm_w1 + 16384, l1_nm_w2, l2_nm_w1, l2_nm_w1 + 16384, l2_nm_w2,
      bp_w1, bp_w1 + 128 * 64, pk, pkprod,
      l1_nm_b2, l2_nm_b2, fvec,
      tt, te_w1, te_b1, te_w2, te_b2,
      x_t, cond, X0b, n, ei + E_, E_, deg, nbBuild);
  k_scan1<<<nb, 256, 0, stream>>>(deg, tmp, bsum, n);
  k_scan2<<<1, 256, 0, stream>>>(bsum, nb);
  k_scan3<<<nb, 256, 0, stream>>>(deg, tmp, bsum, rowp, cursor, n);

  // scatter || quad GEMM (P1,Q1,P2a,Q2a)
  k_quad_scatter<<<nscat + ngemm, 256, 0, stream>>>(
      X0b, pk, l1_nm_b1, Pbf, Qbf, P2a, Q2a, n, nscat,
      ei, E_, nE, cursor, csr32,
      pos, l1_cm_w1, l1_cm_b1, l1_cm_w2, l1_cm_b2);

  k_aggregate<true><<<nagg, 256, 0, stream>>>(rowp, csr32, nullptr, Pbf, Qbf,
      l1_nm_w1 + 256 * 128, pos, pos1, degf, Sb1, n);

  // dual-resid GEMM (P2,Q2) || aux2
  k_dualresid_aux<<<ngemm + nscat, 256, 0, stream>>>(
      Sb1, pkprod, fvec, l2_nm_b1, P2a, Q2a, degf, Pbf, Qbf, n, ngemm,
      csr32, nE, pos1, auxd);

  k_aggregate<false><<<nagg, 256, 0, stream>>>(rowp, csr32, auxd, Pbf, Qbf,
      l2_nm_w1 + 256 * 128, nullptr, nullptr, nullptr, Sb2, n);

  // final: X2 -> d_out + U,V
  k_final<<<ngemm, 256, 0, stream>>>(Sb1, Sb2, X0b, degf, fvec + 256, pk, bp_b1,
                                     (float*)d_out, Ubf, Vbf, n);

  k_bond<<<nscat, 256, 0, stream>>>(csr32, nE, Ubf, Vbf,
                                    bp_w2, bp_b2, (float*)d_out + (size_t)n * 64);
}

// Round 20
// 284.193 us; speedup vs baseline: 1.0546x; 1.0546x over previous
//
#include <hip/hip_runtime.h>
#include <hip/hip_bf16.h>
#include <stdint.h>

typedef float  f32x4 __attribute__((ext_vector_type(4)));
typedef short  s16x8 __attribute__((ext_vector_type(8)));
typedef unsigned short u16x8 __attribute__((ext_vector_type(8)));
typedef unsigned short ushort_t;

__device__ __forceinline__ short f2bf(float f) {
  union { float f; unsigned u; } x; x.f = f;
  unsigned r = x.u + 0x7fffu + ((x.u >> 16) & 1u);
  return (short)(r >> 16);
}
__device__ __forceinline__ float bf2f(unsigned short u) {
  union { unsigned u; float f; } x; x.u = ((unsigned)u) << 16; return x.f;
}
__device__ __forceinline__ float i2f(int v) {
  union { int i; float f; } x; x.i = v; return x.f;
}
__device__ __forceinline__ int f2i(float v) {
  union { float f; int i; } x; x.f = v; return x.i;
}

__device__ __forceinline__ void pack_one(const float* W, int cols, int local, short* dst) {
  int NT = cols / 16;
  int j = local & 7, l = (local >> 3) & 63;
  int nt = (local >> 9) % NT;
  int kt = (local >> 9) / NT;
  int k = kt * 32 + ((l >> 4) * 8) + j;
  int ncol = nt * 16 + (l & 15);
  dst[local] = f2bf(W[(size_t)k * cols + ncol]);
}

// ---------------- front: weight pack + build_xin (temb in-block) + deg_count
__global__ __launch_bounds__(256)
void k_front(const float* __restrict__ w0, const float* __restrict__ w1,
             const float* __restrict__ w2, const float* __restrict__ w3,
             const float* __restrict__ w4, const float* __restrict__ w5,
             const float* __restrict__ w6, const float* __restrict__ w7,
             short* __restrict__ out,
             const int* __restrict__ t, const float* __restrict__ tw1,
             const float* __restrict__ tb1, const float* __restrict__ tw2,
             const float* __restrict__ tb2,
             const float* __restrict__ xt, const float* __restrict__ cond,
             ushort_t* __restrict__ X, int n,
             const int* __restrict__ edst, int E, int* __restrict__ deg,
             int nbBuild) {
  int b = blockIdx.x;
  if (b < 448) {
    int i = b * 256 + threadIdx.x;
    if (i < 98304) {
      int r = i >> 14, local = i & 16383;
      const float* W = r == 0 ? w0 : r == 1 ? w1 : r == 2 ? w2 : r == 3 ? w3 : r == 4 ? w4 : w5;
      pack_one(W, 128, local, out + r * 16384);
    } else {
      int j = i - 98304;
      int r = j >> 13, local = j & 8191;
      pack_one(r ? w7 : w6, 64, local, out + 98304 + r * 8192);
    }
    return;
  }
  b -= 448;
  if (b < nbBuild) {
    __shared__ float h[32], tembL[32];
    int j = threadIdx.x;
    if (j < 32) h[j] = fmaxf(((float)t[0] / 1000.0f) * tw1[j] + tb1[j], 0.f);
    __syncthreads();
    if (j < 32) {
      float acc = tb2[j];
      for (int k2 = 0; k2 < 32; ++k2) acc += h[k2] * tw2[k2 * 32 + j];
      tembL[j] = acc;
    }
    __syncthreads();
    int i = b * 256 + threadIdx.x;
    if (i >= n * 16) return;
    int node = i >> 4, c8 = i & 15;
    float va[8];
    if (c8 < 8)       { const float* p = &xt[(size_t)node * 64 + c8 * 8];
                        #pragma unroll
                        for (int q = 0; q < 8; ++q) va[q] = p[q]; }
    else if (c8 < 12) { const float* p = &cond[(c8 - 8) * 8];
                        #pragma unroll
                        for (int q = 0; q < 8; ++q) va[q] = p[q]; }
    else              { const float* p = &tembL[(c8 - 12) * 8];
                        #pragma unroll
                        for (int q = 0; q < 8; ++q) va[q] = p[q]; }
    u16x8 o;
    #pragma unroll
    for (int q = 0; q < 8; ++q) o[q] = f2bf(va[q]);
    *(u16x8*)&X[(size_t)node * 128 + c8 * 8] = o;
    return;
  }
  b -= nbBuild;
  int e = b * 256 + threadIdx.x;
  if (e < E) atomicAdd(&deg[edst[e]], 1);
}

// ---------------- scans (self-loop +1 folded in)
__global__ void k_scan1(const int* __restrict__ deg, int* __restrict__ tmp,
                        int* __restrict__ bsum, int n) {
  __shared__ int sh[256];
  int i = blockIdx.x * 256 + threadIdx.x;
  int v = (i < n) ? deg[i] + 1 : 0;
  sh[threadIdx.x] = v; __syncthreads();
  for (int off = 1; off < 256; off <<= 1) {
    int t = (threadIdx.x >= off) ? sh[threadIdx.x - off] : 0;
    __syncthreads();
    sh[threadIdx.x] += t;
    __syncthreads();
  }
  if (i < n) tmp[i] = sh[threadIdx.x];
  if (threadIdx.x == 255) bsum[blockIdx.x] = sh[255];
}
__global__ void k_scan2(int* __restrict__ bsum, int nb) {
  __shared__ int sh[256];
  int t = threadIdx.x;
  int v = (t < nb) ? bsum[t] : 0;
  sh[t] = v; __syncthreads();
  for (int off = 1; off < 256; off <<= 1) {
    int u = (t >= off) ? sh[t - off] : 0;
    __syncthreads();
    sh[t] += u;
    __syncthreads();
  }
  if (t < nb) bsum[t] = sh[t] - v;
}
__global__ void k_scan3(const int* __restrict__ deg, const int* __restrict__ tmp,
                        const int* __restrict__ bsum, int* __restrict__ row,
                        int* __restrict__ cursor, int n) {
  int i = blockIdx.x * 256 + threadIdx.x;
  if (i < n) {
    int incl = tmp[i] + bsum[i >> 8];
    row[i + 1] = incl;
    cursor[(size_t)i * 32] = incl - (deg[i] + 1);
    if (i == 0) row[0] = 0;
  }
}

// dual-GEMM body, two-phase 32KB staging (A frags persist in regs)
__device__ __forceinline__
void dual_body(const ushort_t* A, const short* Wp, const float* bias1,
               ushort_t* out1, ushort_t* out2, int n, int bid, short* BL) {
  const int NT = 8;
  int t = threadIdx.x, wid = t >> 6, lane = t & 63;
  int cg = lane >> 4;
  int ntiles = (n + 15) >> 4;
  int tile = bid * 4 + wid;
  bool valid = tile < ntiles;
  int r0 = (valid ? tile : 0) << 4;
  int arow = r0 + (lane & 15);
  int crow = arow < n ? arow : 0;
  const ushort_t* Ar = A + (size_t)crow * 128;
  s16x8 Af[4];
  #pragma unroll
  for (int kt = 0; kt < 4; ++kt)
    Af[kt] = *(const s16x8*)(Ar + kt * 32 + cg * 8);
  float bb[NT];
  #pragma unroll
  for (int nt = 0; nt < NT; ++nt)
    bb[nt] = bias1 ? bias1[nt * 16 + (lane & 15)] : 0.f;
  #pragma unroll
  for (int w = 0; w < 2; ++w) {
    for (int i = threadIdx.x; i < 2048; i += 256)
      ((int4*)BL)[i] = ((const int4*)Wp)[w * 2048 + i];
    __syncthreads();
    ushort_t* outp = w ? out2 : out1;
    #pragma unroll
    for (int nt = 0; nt < NT; ++nt) {
      f32x4 acc = {0.f, 0.f, 0.f, 0.f};
      #pragma unroll
      for (int kt = 0; kt < 4; ++kt) {
        s16x8 bfr = *(const s16x8*)&BL[((kt * NT + nt) * 64 + lane) * 8];
        acc = __builtin_amdgcn_mfma_f32_16x16x32_bf16(Af[kt], bfr, acc, 0, 0, 0);
      }
      int ncol = nt * 16 + (lane & 15);
      float badd = w ? 0.f : bb[nt];
      #pragma unroll
      for (int reg = 0; reg < 4; ++reg) {
        int rr = r0 + cg * 4 + reg;
        if (valid && rr < n)
          outp[(size_t)rr * 128 + ncol] = (ushort_t)f2bf(acc[reg] + badd);
      }
    }
    if (w == 0) __syncthreads();
  }
}

// ---------------- hybrid: layer-1 dual GEMM (two-phase) || scatter -> combined 32B struct
// csr32[slot] = int4{s, d, eid, bits(dist)} , int4{bits(hx), bits(hy), bits(hz), 0}
__global__ __launch_bounds__(256)
void k_dual_scatter(const ushort_t* __restrict__ A, const short* __restrict__ Wp,
                    const float* __restrict__ bias1,
                    ushort_t* __restrict__ out1, ushort_t* __restrict__ out2,
                    int n, int ngemm,
                    const int* __restrict__ ei, int E, int nE,
                    int* __restrict__ cursor, int4* __restrict__ csr32,
                    const float* __restrict__ pos,
                    const float* __restrict__ cw1, const float* __restrict__ cb1,
                    const float* __restrict__ cw2, const float* __restrict__ cb2) {
  __shared__ short BL[128 * 128];        // 32KB
  if ((int)blockIdx.x < ngemm) {
    dual_body(A, Wp, bias1, out1, out2, n, blockIdx.x, BL);
    return;
  }
  int e = (blockIdx.x - ngemm) * 256 + threadIdx.x;
  if (e >= nE) return;
  int s, d, id;
  if (e < E) { s = ei[e]; d = ei[E + e]; id = e; }
  else       { s = d = e - E; id = -1; }
  int slot = atomicAdd(&cursor[(size_t)d * 32], 1);
  float dx = pos[s*3+0] - pos[d*3+0];
  float dy = pos[s*3+1] - pos[d*3+1];
  float dz = pos[s*3+2] - pos[d*3+2];
  float dist = sqrtf(dx*dx + dy*dy + dz*dz + 1e-8f);
  float hh = cb2[0];
  #pragma unroll 4
  for (int j = 0; j < 128; ++j)
    hh += fmaxf(fmaf(dist, cw1[j], cb1[j]), 0.f) * cw2[j];
  int4 c0; c0.x = s; c0.y = d; c0.z = id; c0.w = f2i(dist);
  int4 c1; c1.x = f2i(hh * dx); c1.y = f2i(hh * dy); c1.z = f2i(hh * dz); c1.w = 0;
  csr32[(size_t)slot * 2 + 0] = c0;
  csr32[(size_t)slot * 2 + 1] = c1;
}

// standalone two-phase dual (layer 2)
__global__ __launch_bounds__(256)
void k_mgemm_dual2(const ushort_t* __restrict__ A, const short* __restrict__ Wp,
                   const float* __restrict__ bias1,
                   ushort_t* __restrict__ out1, ushort_t* __restrict__ out2, int n) {
  __shared__ short BL[128 * 128];
  dual_body(A, Wp, bias1, out1, out2, n, blockIdx.x, BL);
}

// ---------------- single node GEMM body (32KB)
__device__ __forceinline__
void mgemm_body(const ushort_t* A, const short* Wp, const float* bias,
                const ushort_t* resid, const float* degf, ushort_t* out,
                float* out64, int n, int bid, short* BL) {
  const int NT = 8;
  for (int i = threadIdx.x; i < 2048; i += 256)
    ((int4*)BL)[i] = ((const int4*)Wp)[i];
  __syncthreads();
  int t = threadIdx.x, wid = t >> 6, lane = t & 63;
  int cg = lane >> 4;
  float bb[NT];
  #pragma unroll
  for (int nt = 0; nt < NT; ++nt)
    bb[nt] = bias ? bias[nt * 16 + (lane & 15)] : 0.f;
  int ntiles = (n + 15) >> 4;
  int tile = bid * 4 + wid;
  if (tile >= ntiles) return;
  int r0 = tile << 4;
  int arow = r0 + (lane & 15);
  int crow = arow < n ? arow : 0;
  const ushort_t* Ar = A + (size_t)crow * 128;
  s16x8 Af[4];
  #pragma unroll
  for (int kt = 0; kt < 4; ++kt)
    Af[kt] = *(const s16x8*)(Ar + kt * 32 + cg * 8);
  float dsc[4];
  #pragma unroll
  for (int reg = 0; reg < 4; ++reg) {
    int rr = r0 + cg * 4 + reg;
    dsc[reg] = degf ? degf[rr < n ? rr : 0] : 1.f;
  }
  #pragma unroll
  for (int nt = 0; nt < NT; ++nt) {
    f32x4 acc = {0.f, 0.f, 0.f, 0.f};
    #pragma unroll
    for (int kt = 0; kt < 4; ++kt) {
      s16x8 bfr = *(const s16x8*)&BL[((kt * NT + nt) * 64 + lane) * 8];
      acc = __builtin_amdgcn_mfma_f32_16x16x32_bf16(Af[kt], bfr, acc, 0, 0, 0);
    }
    int ncol = nt * 16 + (lane & 15);
    #pragma unroll
    for (int reg = 0; reg < 4; ++reg) {
      int rr = r0 + cg * 4 + reg;
      if (rr < n) {
        float v = acc[reg] + dsc[reg] * bb[nt];
        if (resid) v += bf2f(resid[(size_t)rr * 128 + ncol]);
        out[(size_t)rr * 128 + ncol] = (ushort_t)f2bf(v);
        if (out64 && ncol < 64) out64[(size_t)rr * 64 + ncol] = v;
      }
    }
  }
}

__global__ __launch_bounds__(256)
void k_mgemm(const ushort_t* __restrict__ A, const short* __restrict__ Wp,
             const float* __restrict__ bias, const ushort_t* __restrict__ resid,
             const float* __restrict__ degf, ushort_t* __restrict__ out,
             float* __restrict__ out64, int n) {
  __shared__ short BL[128 * 128];
  mgemm_body(A, Wp, bias, resid, degf, out, out64, n, blockIdx.x, BL);
}

// hybrid: post-GEMM layer1 || aux2 (dist for layer 2, reads csr32)
__global__ __launch_bounds__(256)
void k_post_aux(const ushort_t* __restrict__ A, const short* __restrict__ Wp,
                const float* __restrict__ bias, const ushort_t* __restrict__ resid,
                const float* __restrict__ degf, ushort_t* __restrict__ out,
                int n, int ngemm,
                const int4* __restrict__ csr32,
                int nE, const float* __restrict__ pos1, float* __restrict__ auxd) {
  __shared__ short BL[128 * 128];
  if ((int)blockIdx.x < ngemm) {
    mgemm_body(A, Wp, bias, resid, degf, out, nullptr, n, blockIdx.x, BL);
    return;
  }
  int k = (blockIdx.x - ngemm) * 256 + threadIdx.x;
  if (k >= nE) return;
  int4 c = csr32[(size_t)k * 2];
  int s = c.x, d = c.y;
  float dx = pos1[s*3+0] - pos1[d*3+0];
  float dy = pos1[s*3+1] - pos1[d*3+1];
  float dz = pos1[s*3+2] - pos1[d*3+2];
  auxd[k] = sqrtf(dx*dx + dy*dy + dz*dz + 1e-8f);
}

// ---------------- bond-pre dual GEMM (COLS=64, 32KB single-phase)
__global__ __launch_bounds__(256)
void k_mgemm_dual64(const ushort_t* __restrict__ A, const short* __restrict__ Wp,
                    const float* __restrict__ bias1,
                    ushort_t* __restrict__ out1, ushort_t* __restrict__ out2, int n) {
  const int COLS = 64, NT = 4;
  __shared__ short BL[2 * 128 * COLS];
  for (int i = threadIdx.x; i < 2 * 128 * COLS / 8; i += 256)
    ((int4*)BL)[i] = ((const int4*)Wp)[i];
  __syncthreads();
  int t = threadIdx.x, wid = t >> 6, lane = t & 63;
  int cg = lane >> 4;
  float bb[NT];
  #pragma unroll
  for (int nt = 0; nt < NT; ++nt)
    bb[nt] = bias1 ? bias1[nt * 16 + (lane & 15)] : 0.f;
  int ntiles = (n + 15) >> 4;
  for (int tile = blockIdx.x * 4 + wid; tile < ntiles; tile += gridDim.x * 4) {
    int r0 = tile << 4;
    int arow = r0 + (lane & 15);
    int crow = arow < n ? arow : 0;
    const ushort_t* Ar = A + (size_t)crow * 128;
    s16x8 Af[4];
    #pragma unroll
    for (int kt = 0; kt < 4; ++kt)
      Af[kt] = *(const s16x8*)(Ar + kt * 32 + cg * 8);
    #pragma unroll
    for (int w = 0; w < 2; ++w) {
      ushort_t* outp = w ? out2 : out1;
      #pragma unroll
      for (int nt = 0; nt < NT; ++nt) {
        f32x4 acc = {0.f, 0.f, 0.f, 0.f};
        #pragma unroll
        for (int kt = 0; kt < 4; ++kt) {
          s16x8 bfr = *(const s16x8*)&BL[(w * 128 * COLS / 8 + (kt * NT + nt) * 64 + lane) * 8];
          acc = __builtin_amdgcn_mfma_f32_16x16x32_bf16(Af[kt], bfr, acc, 0, 0, 0);
        }
        int ncol = nt * 16 + (lane & 15);
        float badd = w ? 0.f : bb[nt];
        #pragma unroll
        for (int reg = 0; reg < 4; ++reg) {
          int rr = r0 + cg * 4 + reg;
          if (rr < n)
            outp[(size_t)rr * COLS + ncol] = (ushort_t)f2bf(acc[reg] + badd);
        }
      }
    }
  }
}

// ---------------- per-dst aggregation (half-stream pipeline, csr32 reads)
template<bool L1>
__global__ __launch_bounds__(256)
void k_aggregate(const int* __restrict__ row, const int4* __restrict__ csr32,
                 const float* __restrict__ auxd,
                 const ushort_t* __restrict__ Pb, const ushort_t* __restrict__ Qb,
                 const float* __restrict__ w1r,
                 const float* __restrict__ posin, float* __restrict__ posout,
                 float* __restrict__ degf, ushort_t* __restrict__ Sb, int n) {
  int gw = (blockIdx.x * 256 + threadIdx.x) >> 6;
  if (gw >= n) return;
  int lane = threadIdx.x & 63;
  int half = lane >> 5, sub = lane & 31;
  int r0 = row[gw], r1 = row[gw + 1];
  int r1m1 = r1 - 1;

  ushort4 pu = *(const ushort4*)&Pb[(size_t)gw * 128 + (sub << 2)];
  float p0 = bf2f(pu.x), p1 = bf2f(pu.y), p2 = bf2f(pu.z), p3 = bf2f(pu.w);
  float4 wv = *(const float4*)&w1r[sub << 2];
  float a0 = 0.f, a1 = 0.f, a2 = 0.f, a3 = 0.f, pacc = 0.f;

  int k0 = r0 + half;
  bool any = k0 < r1;
  int kA = k0 < r1m1 ? k0 : r1m1;
  int kB = k0 + 2 < r1m1 ? k0 + 2 : r1m1;
  int4 cA = csr32[(size_t)kA * 2];
  int sB = csr32[(size_t)kB * 2].x;
  ushort4 qA = *(const ushort4*)&Qb[(size_t)cA.x * 128 + (sub << 2)];
  float dA, dB;
  float4 hA, hB;
  if (L1) { hA = *(const float4*)&csr32[(size_t)kA * 2 + 1]; dA = i2f(cA.w); }
  else    { dA = auxd[kA]; }

  for (int k = k0; k + 2 < r1; k += 2) {
    int kn4 = k + 4 < r1m1 ? k + 4 : r1m1;
    int kc2 = k + 2;
    int sC = csr32[(size_t)kn4 * 2].x;
    ushort4 qB = *(const ushort4*)&Qb[(size_t)sB * 128 + (sub << 2)];
    if (L1) {
      int4 cB2 = csr32[(size_t)kc2 * 2];
      hB = *(const float4*)&csr32[(size_t)kc2 * 2 + 1];
      dB = i2f(cB2.w);
    } else {
      dB = auxd[kc2];
    }
    a0 += fmaxf(fmaf(dA, wv.x, p0 + bf2f(qA.x)), 0.f);
    a1 += fmaxf(fmaf(dA, wv.y, p1 + bf2f(qA.y)), 0.f);
    a2 += fmaxf(fmaf(dA, wv.z, p2 + bf2f(qA.z)), 0.f);
    a3 += fmaxf(fmaf(dA, wv.w, p3 + bf2f(qA.w)), 0.f);
    if (L1 && sub < 3) pacc += (sub == 0) ? hA.x : (sub == 1) ? hA.y : hA.z;
    qA = qB; dA = dB; hA = hB; sB = sC;
  }
  if (any) {
    a0 += fmaxf(fmaf(dA, wv.x, p0 + bf2f(qA.x)), 0.f);
    a1 += fmaxf(fmaf(dA, wv.y, p1 + bf2f(qA.y)), 0.f);
    a2 += fmaxf(fmaf(dA, wv.z, p2 + bf2f(qA.z)), 0.f);
    a3 += fmaxf(fmaf(dA, wv.w, p3 + bf2f(qA.w)), 0.f);
    if (L1 && sub < 3) pacc += (sub == 0) ? hA.x : (sub == 1) ? hA.y : hA.z;
  }

  a0 += __shfl_xor(a0, 32, 64);
  a1 += __shfl_xor(a1, 32, 64);
  a2 += __shfl_xor(a2, 32, 64);
  a3 += __shfl_xor(a3, 32, 64);
  if (L1) pacc += __shfl_xor(pacc, 32, 64);

  if (half == 0) {
    ushort4 o;
    o.x = (ushort_t)f2bf(a0); o.y = (ushort_t)f2bf(a1);
    o.z = (ushort_t)f2bf(a2); o.w = (ushort_t)f2bf(a3);
    *(ushort4*)&Sb[(size_t)gw * 128 + (sub << 2)] = o;
  }
  if (L1) {
    if (lane < 3) posout[gw * 3 + lane] = posin[gw * 3 + lane] + pacc;
    if (lane == 0) degf[gw] = (float)(r1 - r0);
  }
}

// ---------------- bond predictor in CSR(dst) order (csr32 reads)
__global__ __launch_bounds__(256)
void k_bond(const int4* __restrict__ csr32, int nE,
            const ushort_t* __restrict__ U, const ushort_t* __restrict__ V,
            const float* __restrict__ w2, const float* __restrict__ b2,
            float* __restrict__ out) {
  __shared__ float w2L[256];
  w2L[threadIdx.x] = w2[threadIdx.x];
  __syncthreads();
  int k = blockIdx.x * 256 + threadIdx.x;
  if (k >= nE) return;
  int4 c = csr32[(size_t)k * 2];
  int eid = c.z;
  if (eid < 0) return;
  int s = c.x, d = c.y;
  const ushort_t* Ur = U + (size_t)s * 64;
  const ushort_t* Vr = V + (size_t)d * 64;
  float l0 = b2[0], l1 = b2[1], l2 = b2[2], l3 = b2[3];
  #pragma unroll
  for (int c8 = 0; c8 < 8; ++c8) {
    u16x8 u = *(const u16x8*)(Ur + c8 * 8);
    u16x8 v = *(const u16x8*)(Vr + c8 * 8);
    #pragma unroll
    for (int j = 0; j < 8; ++j) {
      float h = fmaxf(bf2f(u[j]) + bf2f(v[j]), 0.f);
      const float* wr = &w2L[(c8 * 8 + j) * 4];
      l0 = fmaf(h, wr[0], l0);
      l1 = fmaf(h, wr[1], l1);
      l2 = fmaf(h, wr[2], l2);
      l3 = fmaf(h, wr[3], l3);
    }
  }
  float4 o = {l0, l1, l2, l3};
  *(float4*)&out[(size_t)eid * 4] = o;
}

extern "C" void kernel_launch(void* const* d_in, const int* in_sizes, int n_in,
                              void* d_out, int out_size, void* d_ws, size_t ws_size,
                              hipStream_t stream) {
  const float* x_t   = (const float*)d_in[0];
  const float* pos   = (const float*)d_in[1];
  const int*   ei    = (const int*)d_in[2];
  const int*   tt    = (const int*)d_in[3];
  const float* cond  = (const float*)d_in[4];
  const float* te_w1 = (const float*)d_in[5];
  const float* te_b1 = (const float*)d_in[6];
  const float* te_w2 = (const float*)d_in[7];
  const float* te_b2 = (const float*)d_in[8];
  const float* l1_nm_w1 = (const float*)d_in[9];
  const float* l1_nm_b1 = (const float*)d_in[10];
  const float* l1_nm_w2 = (const float*)d_in[11];
  const float* l1_nm_b2 = (const float*)d_in[12];
  const float* l1_cm_w1 = (const float*)d_in[13];
  const float* l1_cm_b1 = (const float*)d_in[14];
  const float* l1_cm_w2 = (const float*)d_in[15];
  const float* l1_cm_b2 = (const float*)d_in[16];
  const float* l2_nm_w1 = (const float*)d_in[17];
  const float* l2_nm_b1 = (const float*)d_in[18];
  const float* l2_nm_w2 = (const float*)d_in[19];
  const float* l2_nm_b2 = (const float*)d_in[20];
  const float* bp_w1 = (const float*)d_in[25];
  const float* bp_b1 = (const float*)d_in[26];
  const float* bp_w2 = (const float*)d_in[27];
  const float* bp_b2 = (const float*)d_in[28];

  int n  = in_sizes[0] / 64;
  int E_ = in_sizes[2] / 2;
  int nE = E_ + n;
  int nb = (n + 255) / 256;

  uintptr_t base = (uintptr_t)d_ws;
  size_t off = 0;
  auto alloc = [&](size_t bytes) -> void* {
    void* p = (void*)(base + off);
    off += (bytes + 255) & ~(size_t)255;
    return p;
  };
  short* pk    = (short*)alloc(114688 * 2);
  short* pk_l1_t = pk;
  short* pk_l1_2 = pk + 32768;
  short* pk_l2_t = pk + 49152;
  short* pk_l2_2 = pk + 81920;
  short* pk_bp_t = pk + 98304;
  ushort_t* X0b = (ushort_t*)alloc((size_t)n * 128 * 2);
  ushort_t* X1b = (ushort_t*)alloc((size_t)n * 128 * 2);
  ushort_t* Sb  = (ushort_t*)alloc((size_t)n * 128 * 2);
  ushort_t* Pbf = (ushort_t*)alloc((size_t)n * 128 * 2);
  ushort_t* Qbf = (ushort_t*)alloc((size_t)n * 128 * 2);
  int*   deg    = (int*)alloc((size_t)n * 4);
  int*   tmp    = (int*)alloc((size_t)n * 4);
  int*   bsum   = (int*)alloc(256 * 4);
  int*   rowp   = (int*)alloc(((size_t)n + 1) * 4);
  int*   cursor = (int*)alloc((size_t)n * 128);
  int4*  csr32  = (int4*)alloc((size_t)nE * 32);
  float* auxd   = (float*)alloc((size_t)nE * 4);
  float* degf   = (float*)alloc((size_t)n * 4);
  float* pos1   = (float*)alloc((size_t)n * 3 * 4);
  ushort_t* Ubf = Pbf;
  ushort_t* Vbf = Qbf;

  int nbBuild = (n * 16 + 255) / 256;
  int ndc = (E_ + 255) / 256;
  int nscat = (nE + 255) / 256;
  int nagg = (n + 3) / 4;
  int ngemm = (((n + 15) >> 4) + 3) / 4;

  hipMemsetAsync(deg, 0, (size_t)n * 4, stream);
  k_front<<<448 + nbBuild + ndc, 256, 0, stream>>>(
      l1_nm_w1, l1_nm_w1 + 16384, l1_nm_w2, l2_nm_w1, l2_nm_w1 + 16384, l2_nm_w2,
      bp_w1, bp_w1 + 128 * 64, pk,
      tt, te_w1, te_b1, te_w2, te_b2,
      x_t, cond, X0b, n, ei + E_, E_, deg, nbBuild);
  k_scan1<<<nb, 256, 0, stream>>>(deg, tmp, bsum, n);
  k_scan2<<<1, 256, 0, stream>>>(bsum, nb);
  k_scan3<<<nb, 256, 0, stream>>>(deg, tmp, bsum, rowp, cursor, n);

  // layer-1 dual GEMM (two-phase 32KB) || scatter (combined 32B struct)
  k_dual_scatter<<<ngemm + nscat, 256, 0, stream>>>(
      X0b, pk_l1_t, l1_nm_b1, Pbf, Qbf, n, ngemm,
      ei, E_, nE, cursor, csr32,
      pos, l1_cm_w1, l1_cm_b1, l1_cm_w2, l1_cm_b2);

  k_aggregate<true><<<nagg, 256, 0, stream>>>(rowp, csr32, nullptr, Pbf, Qbf,
      l1_nm_w1 + 256 * 128, pos, pos1, degf, Sb, n);

  // post-GEMM layer1 || aux2
  k_post_aux<<<ngemm + nscat, 256, 0, stream>>>(
      Sb, pk_l1_2, l1_nm_b2, X0b, degf, X1b, n, ngemm,
      csr32, nE, pos1, auxd);

  // layer 2
  k_mgemm_dual2<<<ngemm, 256, 0, stream>>>(X1b, pk_l2_t, l2_nm_b1, Pbf, Qbf, n);
  k_aggregate<false><<<nagg, 256, 0, stream>>>(rowp, csr32, auxd, Pbf, Qbf,
      l2_nm_w1 + 256 * 128, nullptr, nullptr, nullptr, Sb, n);
  k_mgemm<<<ngemm, 256, 0, stream>>>(Sb, pk_l2_2, l2_nm_b2, X1b, degf, X0b, (float*)d_out, n);

  // bond predictor
  k_mgemm_dual64<<<ngemm, 256, 0, stream>>>(X0b, pk_bp_t, bp_b1, Ubf, Vbf, n);
  k_bond<<<nscat, 256, 0, stream>>>(csr32, nE, Ubf, Vbf,
                                    bp_w2, bp_b2, (float*)d_out + (size_t)n * 64);
}